// Round 9
// baseline (2454.583 us; speedup 1.0000x reference)
//
#include <hip/hip_runtime.h>
#include <cstdint>
#include <cstddef>

// BottomUpNet: N=8192 rows independent; K=16 sequential steps.
// R20: prefetch depth 1 -> 3. R18/R19 counter-fit: per-K-tile cost =
// ~2150 cyc FIXED + MFMA (split 3176 = 2150+1024; h 2662 = 2150+512) —
// the constant, not the work, dominates. 2150 cyc ≈ effective global->LDS
// latency; with depth-1 prefetch the loop self-locks at T ≈ L (R13 depth-0
// and R18 depth-1 measured the same, as the lock predicts). Fix: 5 LDS
// buffer sets (120 KB), tiles t+1..t+3 in flight (18 loads), vmcnt(12)
// retires only t+1 — never drains deeper mid-loop.
// Hazard audit: STAGE(t+3)->buf (t+3)%5, last read by DSREAD at tile t-2,
// lgkm-drained 2 barriers before the write (R18's margin). MFMA order per
// output element unchanged: absmax must stay exactly 1.192093e-07.
// R19's algorithmic wins kept: pure-fp16 weights (1 MFMA), K1m+K1h fused
// via W1cat (4 GEMMs/step), fused pred-dot epilogue.

typedef _Float16 f16x8 __attribute__((ext_vector_type(8)));
typedef float f32x16 __attribute__((ext_vector_type(16)));

#define MF(d, a, b) d = __builtin_amdgcn_mfma_f32_32x32x16_f16(a, b, d, 0, 0, 0)
#define CFENCE() asm volatile("" ::: "memory")

__device__ __forceinline__ void gload16(const void* g, void* l) {
  // async global->LDS, 16B/lane, LDS dest = wave-uniform base + lane*16
  __builtin_amdgcn_global_load_lds(
      (__attribute__((address_space(1))) void*)const_cast<void*>(g),
      (__attribute__((address_space(3))) void*)l,
      16, 0, 0);
}

// ---- fp16 GEMM: C = relu(A@B^T + bias) fp16 out,
// or fused-pred mode (sacc != null): sacc[row] += sum_col relu(.)*w3[col]
// Tile 256x128, BK=32, 4 waves (128x64 each), 5-buffer depth-3 pipeline.
__global__ __launch_bounds__(256, 1)
void gemm_h_kernel(const _Float16* __restrict__ A0, int ldA0,
                   const _Float16* __restrict__ A1, int ldA1,
                   int kcut, int Ktot,
                   const _Float16* __restrict__ B,
                   const float* __restrict__ bias,
                   _Float16* __restrict__ C, int ldC,
                   const float* __restrict__ w3, float* __restrict__ sacc)
{
  __shared__ _Float16 sA[5][256 * 32];   // 80 KB
  __shared__ _Float16 sB[5][128 * 32];   // 40 KB

  const int lane = threadIdx.x & 63;
  const int wave = threadIdx.x >> 6;
  const int wm = (wave >> 1) * 128, wn = (wave & 1) * 64;
  const int mBase = blockIdx.x * 256, nBase = blockIdx.y * 128;

  // paired-row staging layout (R13-verified): chunk = 16 logical rows
  const int lr  = 2 * (lane >> 3) + ((lane >> 2) & 1);
  const int lcs = (((lane & 3) ^ ((lane >> 3) & 3)) * 8);

  const int l31 = lane & 31, l5 = lane >> 5;
  const int rowoff = (l31 >> 1) * 64 + (l31 & 1) * 32;
  const int fswz = (l31 >> 1) & 3;
  const int ko0 = (l5 ^ fswz) * 8;
  const int ko1 = ((2 + l5) ^ fswz) * 8;

  const _Float16 *aS0[4], *aS1[4], *bS[2];
#pragma unroll
  for (int q = 0; q < 4; ++q) {
    const int row = mBase + (wave + q * 4) * 16 + lr;
    aS0[q] = A0 + (size_t)row * ldA0 + lcs;
    aS1[q] = A1 + (size_t)row * ldA1 + lcs;
  }
#pragma unroll
  for (int q = 0; q < 2; ++q) {
    const int row = nBase + (wave + q * 4) * 16 + lr;
    bS[q] = B + (size_t)row * Ktot + lcs;
  }

  f32x16 acc[4][2];
#pragma unroll
  for (int i = 0; i < 4; ++i)
#pragma unroll
    for (int j = 0; j < 2; ++j) acc[i][j] = (f32x16)0.0f;

  _Float16 *qA0 = &sA[0][0], *qA1 = &sA[1][0], *qA2 = &sA[2][0],
           *qA3 = &sA[3][0], *qA4 = &sA[4][0];
  _Float16 *qB0 = &sB[0][0], *qB1 = &sB[1][0], *qB2 = &sB[2][0],
           *qB3 = &sB[3][0], *qB4 = &sB[4][0];

  auto STAGE = [&](_Float16* dA, _Float16* dB, int kt) {   // 6 loads
    const bool lo = kt < kcut;
    const int kl = lo ? kt : kt - kcut;
#pragma unroll
    for (int q = 0; q < 4; ++q)
      gload16((lo ? aS0[q] : aS1[q]) + kl, dA + (wave + q * 4) * 512);
#pragma unroll
    for (int q = 0; q < 2; ++q)
      gload16(bS[q] + kt, dB + (wave + q * 4) * 512);
  };

  auto DSREAD = [&](const _Float16* pA, const _Float16* pB,
                    f16x8 (&a)[4][2], f16x8 (&b)[2][2]) {  // 12 b128
#pragma unroll
    for (int i = 0; i < 4; ++i) {
      const int base = (wm + i * 32) * 32 + rowoff;
      a[i][0] = *(const f16x8*)(pA + base + ko0);
      a[i][1] = *(const f16x8*)(pA + base + ko1);
    }
#pragma unroll
    for (int j = 0; j < 2; ++j) {
      const int base = (wn + j * 32) * 32 + rowoff;
      b[j][0] = *(const f16x8*)(pB + base + ko0);
      b[j][1] = *(const f16x8*)(pB + base + ko1);
    }
  };

  auto MFMACL = [&](f16x8 (&a)[4][2], f16x8 (&b)[2][2]) {  // 16 MFMA
#pragma unroll
    for (int kh = 0; kh < 2; ++kh)
#pragma unroll
      for (int i = 0; i < 4; ++i)
#pragma unroll
        for (int j = 0; j < 2; ++j) MF(acc[i][j], a[i][kh], b[j][kh]);
  };

  auto ROT = [&]() {   // q0<-q1<-q2<-q3<-q4<-q0 (compile-time pointer swap)
    _Float16* tp;
    tp = qA0; qA0 = qA1; qA1 = qA2; qA2 = qA3; qA3 = qA4; qA4 = tp;
    tp = qB0; qB0 = qB1; qB1 = qB2; qB2 = qB3; qB3 = qB4; qB4 = tp;
  };

  f16x8 aX[4][2], bX[2][2];
  f16x8 aY[4][2], bY[2][2];

  const int NT = Ktot >> 5;                // 32 or 34 (even)
  STAGE(qA0, qB0, 0);
  STAGE(qA1, qB1, 32);
  STAGE(qA2, qB2, 64);
  asm volatile("s_waitcnt vmcnt(12)" ::: "memory");  // tile0 landed
  __builtin_amdgcn_s_barrier();
  CFENCE();
  DSREAD(qA0, qB0, aX, bX);

  for (int t = 0; t < NT; t += 2) {
    // ---- tile t (frags in X); read-ahead t+1 -> Y; stage t+3
    {
      const bool s = (t + 3) < NT;
      if (s) STAGE(qA3, qB3, (t + 3) * 32);
      if (s)                 asm volatile("s_waitcnt vmcnt(12)" ::: "memory");
      else if ((t + 2) < NT) asm volatile("s_waitcnt vmcnt(6)"  ::: "memory");
      else                   asm volatile("s_waitcnt vmcnt(0)"  ::: "memory");
      __builtin_amdgcn_s_barrier();
      CFENCE();
      asm volatile("s_waitcnt lgkmcnt(0)" ::: "memory");  // X-frags ready
      DSREAD(qA1, qB1, aY, bY);                           // t+1 < NT (NT even)
      __builtin_amdgcn_sched_barrier(0);
      __builtin_amdgcn_s_setprio(1);
      MFMACL(aX, bX);
      __builtin_amdgcn_s_setprio(0);
      ROT();
    }
    // ---- tile t+1 (frags in Y); read-ahead t+2 -> X; stage t+4
    {
      const int u = t + 1;
      const bool s = (u + 3) < NT;
      const bool r = (u + 1) < NT;
      if (s) STAGE(qA3, qB3, (u + 3) * 32);
      if (s)                 asm volatile("s_waitcnt vmcnt(12)" ::: "memory");
      else if ((u + 2) < NT) asm volatile("s_waitcnt vmcnt(6)"  ::: "memory");
      else if (r)            asm volatile("s_waitcnt vmcnt(0)"  ::: "memory");
      __builtin_amdgcn_s_barrier();
      CFENCE();
      asm volatile("s_waitcnt lgkmcnt(0)" ::: "memory");  // Y-frags ready
      if (r) DSREAD(qA1, qB1, aX, bX);
      __builtin_amdgcn_sched_barrier(0);
      __builtin_amdgcn_s_setprio(1);
      MFMACL(aY, bY);
      __builtin_amdgcn_s_setprio(0);
      ROT();
    }
  }

  float bv[2], w3v[2];
#pragma unroll
  for (int j = 0; j < 2; ++j) {
    const int col = nBase + wn + j * 32 + l31;
    bv[j] = bias[col];
    w3v[j] = sacc ? w3[col] : 0.0f;
  }

  if (sacc) {
    // fused pred partial: one value per C/D row, reduced over the 32 col-lanes
#pragma unroll
    for (int i = 0; i < 4; ++i)
#pragma unroll
      for (int r = 0; r < 16; ++r) {
        float pr = 0.0f;
#pragma unroll
        for (int j = 0; j < 2; ++j)
          pr += fmaxf(acc[i][j][r] + bv[j], 0.0f) * w3v[j];
        pr += __shfl_xor(pr, 1);
        pr += __shfl_xor(pr, 2);
        pr += __shfl_xor(pr, 4);
        pr += __shfl_xor(pr, 8);
        pr += __shfl_xor(pr, 16);
        if (l31 == 0)
          atomicAdd(&sacc[mBase + wm + i * 32 + (r & 3) + 8 * (r >> 2) + 4 * l5], pr);
      }
  } else {
#pragma unroll
    for (int i = 0; i < 4; ++i)
#pragma unroll
      for (int j = 0; j < 2; ++j)
#pragma unroll
        for (int r = 0; r < 16; ++r) {
          const int row = mBase + wm + i * 32 + (r & 3) + 8 * (r >> 2) + 4 * l5;
          const int col = nBase + wn + j * 32 + l31;
          float v = fmaxf(acc[i][j][r] + bv[j], 0.0f);
          C[(size_t)row * ldC + col] = (_Float16)v;
        }
  }
}

// W (K x N fp32, row-major) -> out (N x K fp16), i.e. transposed
__global__ void wconv_kernel(const float* __restrict__ W, int K, int N,
                             _Float16* __restrict__ oH) {
  int idx = blockIdx.x * 256 + threadIdx.x;   // idx = n*K + k (output-coalesced)
  if (idx >= K * N) return;
  int n = idx / K, k = idx - n * K;
  oH[idx] = (_Float16)W[(size_t)k * N + n];
}

__global__ void init_summary_kernel(const float* __restrict__ agg,
                                    _Float16* __restrict__ sH,
                                    float* __restrict__ sacc) {
  int idx = blockIdx.x * 256 + threadIdx.x;   // 8192*1024
  sH[idx] = (_Float16)agg[idx & 1023];
  if (idx < 8192) sacc[idx] = 0.0f;
}

// bias concat: b1cat = [Mb1 | Ob1] (2048 floats)
__global__ void biascat_kernel(const float* __restrict__ b0,
                               const float* __restrict__ b1,
                               float* __restrict__ o) {
  int idx = blockIdx.x * 256 + threadIdx.x;   // 2048
  o[idx] = (idx < 1024) ? b0[idx] : b1[idx - 1024];
}

// towers [n][k][f] fp32 -> towAll [k][n][f] fp16 (all 16 slices)
__global__ void tow_conv_all_kernel(const float* __restrict__ towers,
                                    _Float16* __restrict__ oH) {
  size_t idx = (size_t)blockIdx.x * 256 + threadIdx.x;  // (k*8192+n)*64+f
  int f = idx & 63;
  int n = (int)((idx >> 6) & 8191);
  int k = (int)(idx >> 19);
  oH[idx] = (_Float16)towers[((size_t)n * 16 + k) * 64 + f];
}

// pred = sigmoid(sacc + Ob3); out *= pred; re-zero sacc for next step
__global__ void pred_final_kernel(float* __restrict__ sacc, const float* __restrict__ b3,
                                  float* __restrict__ out, int step) {
  int row = blockIdx.x * 256 + threadIdx.x;   // 8192
  float p = 1.0f / (1.0f + expf(-(sacc[row] + b3[0])));
  out[row] = (step == 0) ? p : out[row] * p;
  sacc[row] = 0.0f;
}

extern "C" void kernel_launch(void* const* d_in, const int* in_sizes, int n_in,
                              void* d_out, int out_size, void* d_ws, size_t ws_size,
                              hipStream_t stream) {
  const float* towers = (const float*)d_in[0];
  const float* agg    = (const float*)d_in[1];
  const float* MW1 = (const float*)d_in[2];
  const float* Mb1 = (const float*)d_in[3];
  const float* MW2 = (const float*)d_in[4];
  const float* Mb2 = (const float*)d_in[5];
  const float* MW3 = (const float*)d_in[6];
  const float* Mb3 = (const float*)d_in[7];
  const float* OW1 = (const float*)d_in[8];
  const float* Ob1 = (const float*)d_in[9];
  const float* OW2 = (const float*)d_in[10];
  const float* Ob2 = (const float*)d_in[11];
  const float* OW3 = (const float*)d_in[12];
  const float* Ob3 = (const float*)d_in[13];
  float* out = (float*)d_out;

  // ws layout (~95 MiB)
  _Float16* p = (_Float16*)d_ws;
  _Float16* W1catH = p; p += (size_t)2048 * 1088;   // [MW1t rows 0..1023 | OW1t rows 1024..2047]
  _Float16* MW2tH  = p; p += (size_t)1024 * 1024;
  _Float16* OW2tH  = p; p += (size_t)1024 * 1024;
  _Float16* MW3tH  = p; p += (size_t)1024 * 1024;
  _Float16* sumH   = p; p += (size_t)8192 * 1024;
  _Float16* mh1    = p; p += (size_t)8192 * 2048;   // m1 = cols 0..1023, h1 = cols 1024..2047
  _Float16* m2H    = p; p += (size_t)8192 * 1024;
  _Float16* towAllH = p; p += (size_t)16 * 8192 * 64;
  float* sacc  = (float*)p;
  float* b1cat = sacc + 8192;

  // per-call setup: transpose weights (fp16), concat W1/b1, towers, summary
  {
    int tot = 1088 * 1024;
    wconv_kernel<<<dim3((tot + 255) / 256), dim3(256), 0, stream>>>(MW1, 1088, 1024, W1catH);
    wconv_kernel<<<dim3((tot + 255) / 256), dim3(256), 0, stream>>>(OW1, 1088, 1024, W1catH + (size_t)1024 * 1088);
    tot = 1024 * 1024;
    wconv_kernel<<<dim3((tot + 255) / 256), dim3(256), 0, stream>>>(MW2, 1024, 1024, MW2tH);
    wconv_kernel<<<dim3((tot + 255) / 256), dim3(256), 0, stream>>>(OW2, 1024, 1024, OW2tH);
    wconv_kernel<<<dim3((tot + 255) / 256), dim3(256), 0, stream>>>(MW3, 1024, 1024, MW3tH);
    biascat_kernel<<<dim3(8), dim3(256), 0, stream>>>(Mb1, Ob1, b1cat);
    init_summary_kernel<<<dim3(32768), dim3(256), 0, stream>>>(agg, sumH, sacc);
    tow_conv_all_kernel<<<dim3(32768), dim3(256), 0, stream>>>(towers, towAllH);
  }

  const dim3 G1(32, 16), G(32, 8), B256(256);
  for (int k = 0; k < 16; ++k) {
    const _Float16* towH = towAllH + (size_t)k * 8192 * 64;

    // K1 (fused K1m+K1h): x=[sum|tow] @ W1cat^T -> mh1 (m1|h1), N=2048
    gemm_h_kernel<<<G1, B256, 0, stream>>>(sumH, 1024, towH, 64, 1024, 1088,
                                           W1catH, b1cat, mh1, 2048, nullptr, nullptr);
    // K2m: m1 @ MW2^T -> m2
    gemm_h_kernel<<<G, B256, 0, stream>>>(mh1, 2048, mh1, 2048, 1024, 1024,
                                          MW2tH, Mb2, m2H, 1024, nullptr, nullptr);
    // K2h: h1 @ OW2^T -> fused relu+dot(OW3) into sacc
    gemm_h_kernel<<<G, B256, 0, stream>>>(mh1 + 1024, 2048, mh1 + 1024, 2048, 1024, 1024,
                                          OW2tH, Ob2, nullptr, 1024, OW3, sacc);
    // K3: m2 @ MW3^T -> summary
    gemm_h_kernel<<<G, B256, 0, stream>>>(m2H, 1024, m2H, 1024, 1024, 1024,
                                          MW3tH, Mb3, sumH, 1024, nullptr, nullptr);
    // pred + product accumulate + re-zero sacc
    pred_final_kernel<<<dim3(32), dim3(256), 0, stream>>>(sacc, Ob3, out, k);
  }
}

// Round 10
// 2107.104 us; speedup vs baseline: 1.1649x; 1.1649x over previous
//
#include <hip/hip_runtime.h>
#include <cstdint>
#include <cstddef>

// BottomUpNet: N=8192 rows independent; K=16 sequential steps.
// R21 = R11's h-kernel structure x R19's algorithm.
// Ledger reconciliation (R11-R20): per-block-tile fixed cost ~2100 cyc is
// invariant across BK/depth/phase structures => time ~ #K-tiles. R11's
// original h-kernel (128x128 tile, BK=64 -> half the tiles, 32KB LDS ->
// 2 blocks/CU cross-block overlap, naive 1-phase drain) back-solves to
// ~14.7us for 8192x1024x1024 (~1250 TF, 50% peak) — 1.8x faster than all
// my R12-R20 "improvements" (26-29.5us). Deep pipelining was a detour;
// R19's algorithmic wins are orthogonal and kept:
//   - pure-fp16 weights, m-chain 1 MFMA (absmax-verified bit-stable)
//   - K1m+K1h fused via W1cat (2048x1088), 4 GEMMs/step
//   - K2h fused relu+dot(OW3) -> sacc (no h2 materialization)
// gemm_h_kernel below is R11's verbatim (staging layout, loop, epilogue).
// Per-element K-order unchanged: absmax must stay exactly 1.192093e-07.

typedef _Float16 f16x8 __attribute__((ext_vector_type(8)));
typedef float f32x16 __attribute__((ext_vector_type(16)));

__device__ __forceinline__ void gload16(const void* g, void* l) {
  // async global->LDS, 16B/lane, LDS dest = wave-uniform base + lane*16
  __builtin_amdgcn_global_load_lds(
      (__attribute__((address_space(1))) void*)const_cast<void*>(g),
      (__attribute__((address_space(3))) void*)l,
      16, 0, 0);
}

// ---- fp16 GEMM (R11 structure): C = relu(A@B^T + bias) fp16 out,
// or fused-pred mode (sacc != null): sacc[row] += sum_col relu(.)*w3[col]
// Tile 128x128, BK=64, single-buffered 32KB LDS, 256 thr (4 waves, 64x64).
__global__ __launch_bounds__(256, 3)
void gemm_h_kernel(const _Float16* __restrict__ A0, int ldA0,
                   const _Float16* __restrict__ A1, int ldA1,
                   int kcut, int Ktot,
                   const _Float16* __restrict__ B,
                   const float* __restrict__ bias,
                   _Float16* __restrict__ C, int ldC,
                   const float* __restrict__ w3, float* __restrict__ sacc)
{
  __shared__ _Float16 sAh[128 * 64];
  __shared__ _Float16 sBh[128 * 64];

  const int lane = threadIdx.x & 63;
  const int wave = threadIdx.x >> 6;
  const int wm = (wave >> 1) * 64, wn = (wave & 1) * 64;
  const int mBase = blockIdx.x * 128, nBase = blockIdx.y * 128;

  // staging coords: 8 rows/chunk (128 B rows), 8 lanes/row (16 B each);
  // physical seg in LDS = lane-seg, global source seg = lane-seg ^ (row&7)
  const int lr = lane >> 3;                 // row within chunk (0..7)
  const int lcs8 = ((lane & 7) ^ lr) * 8;   // swizzled source seg offset (halves)

  // fragment coords + read-side swizzle (row&7 == l31&7)
  const int l31 = lane & 31, l5 = lane >> 5;
  const int fswz = l31 & 7;

  f32x16 acc[2][2];
#pragma unroll
  for (int i = 0; i < 2; ++i)
#pragma unroll
    for (int j = 0; j < 2; ++j)
      acc[i][j] = (f32x16)0.0f;

  for (int kt = 0; kt < Ktot; kt += 64) {
    const _Float16* aH; int pA, kl;
    if (kt < kcut) { aH = A0; pA = ldA0; kl = kt; }
    else           { aH = A1; pA = ldA1; kl = kt - kcut; }

#pragma unroll
    for (int cc = 0; cc < 4; ++cc) {
      const int c = wave * 4 + cc;                  // chunk 0..15, 8 rows each
      const int arow = mBase + c * 8 + lr;
      const int brow = nBase + c * 8 + lr;
      gload16(aH + (size_t)arow * pA   + kl + lcs8, &sAh[c * 512]);
      gload16(B  + (size_t)brow * Ktot + kt + lcs8, &sBh[c * 512]);
    }
    __syncthreads();

#pragma unroll
    for (int kh = 0; kh < 4; ++kh) {                // four K=16 MFMAs per BK=64
      const int ko = ((kh * 2 + l5) ^ fswz) * 8;    // swizzled seg (0..7)
      f16x8 ah[2], bh[2];
#pragma unroll
      for (int i = 0; i < 2; ++i)
        ah[i] = *(const f16x8*)&sAh[(wm + i * 32 + l31) * 64 + ko];
#pragma unroll
      for (int j = 0; j < 2; ++j)
        bh[j] = *(const f16x8*)&sBh[(wn + j * 32 + l31) * 64 + ko];
#pragma unroll
      for (int i = 0; i < 2; ++i)
#pragma unroll
        for (int j = 0; j < 2; ++j)
          acc[i][j] = __builtin_amdgcn_mfma_f32_32x32x16_f16(ah[i], bh[j], acc[i][j], 0, 0, 0);
    }
    __syncthreads();
  }

  float bv[2], w3v[2];
#pragma unroll
  for (int j = 0; j < 2; ++j) {
    const int col = nBase + wn + j * 32 + l31;
    bv[j] = bias[col];
    w3v[j] = sacc ? w3[col] : 0.0f;
  }

  if (sacc) {
    // fused pred partial: one value per C/D row, reduced over the 32 col-lanes
#pragma unroll
    for (int i = 0; i < 2; ++i)
#pragma unroll
      for (int r = 0; r < 16; ++r) {
        float pr = 0.0f;
#pragma unroll
        for (int j = 0; j < 2; ++j)
          pr += fmaxf(acc[i][j][r] + bv[j], 0.0f) * w3v[j];
        pr += __shfl_xor(pr, 1);
        pr += __shfl_xor(pr, 2);
        pr += __shfl_xor(pr, 4);
        pr += __shfl_xor(pr, 8);
        pr += __shfl_xor(pr, 16);
        if (l31 == 0)
          atomicAdd(&sacc[mBase + wm + i * 32 + (r & 3) + 8 * (r >> 2) + 4 * l5], pr);
      }
  } else {
#pragma unroll
    for (int i = 0; i < 2; ++i)
#pragma unroll
      for (int j = 0; j < 2; ++j)
#pragma unroll
        for (int r = 0; r < 16; ++r) {
          const int row = mBase + wm + i * 32 + (r & 3) + 8 * (r >> 2) + 4 * l5;
          const int col = nBase + wn + j * 32 + l31;
          float v = fmaxf(acc[i][j][r] + bv[j], 0.0f);
          C[(size_t)row * ldC + col] = (_Float16)v;
        }
  }
}

// W (K x N fp32, row-major) -> out (N x K fp16), i.e. transposed
__global__ void wconv_kernel(const float* __restrict__ W, int K, int N,
                             _Float16* __restrict__ oH) {
  int idx = blockIdx.x * 256 + threadIdx.x;   // idx = n*K + k (output-coalesced)
  if (idx >= K * N) return;
  int n = idx / K, k = idx - n * K;
  oH[idx] = (_Float16)W[(size_t)k * N + n];
}

__global__ void init_summary_kernel(const float* __restrict__ agg,
                                    _Float16* __restrict__ sH,
                                    float* __restrict__ sacc) {
  int idx = blockIdx.x * 256 + threadIdx.x;   // 8192*1024
  sH[idx] = (_Float16)agg[idx & 1023];
  if (idx < 8192) sacc[idx] = 0.0f;
}

// bias concat: b1cat = [Mb1 | Ob1] (2048 floats)
__global__ void biascat_kernel(const float* __restrict__ b0,
                               const float* __restrict__ b1,
                               float* __restrict__ o) {
  int idx = blockIdx.x * 256 + threadIdx.x;   // 2048
  o[idx] = (idx < 1024) ? b0[idx] : b1[idx - 1024];
}

// towers [n][k][f] fp32 -> towAll [k][n][f] fp16 (all 16 slices)
__global__ void tow_conv_all_kernel(const float* __restrict__ towers,
                                    _Float16* __restrict__ oH) {
  size_t idx = (size_t)blockIdx.x * 256 + threadIdx.x;  // (k*8192+n)*64+f
  int f = idx & 63;
  int n = (int)((idx >> 6) & 8191);
  int k = (int)(idx >> 19);
  oH[idx] = (_Float16)towers[((size_t)n * 16 + k) * 64 + f];
}

// pred = sigmoid(sacc + Ob3); out *= pred; re-zero sacc for next step
__global__ void pred_final_kernel(float* __restrict__ sacc, const float* __restrict__ b3,
                                  float* __restrict__ out, int step) {
  int row = blockIdx.x * 256 + threadIdx.x;   // 8192
  float p = 1.0f / (1.0f + expf(-(sacc[row] + b3[0])));
  out[row] = (step == 0) ? p : out[row] * p;
  sacc[row] = 0.0f;
}

extern "C" void kernel_launch(void* const* d_in, const int* in_sizes, int n_in,
                              void* d_out, int out_size, void* d_ws, size_t ws_size,
                              hipStream_t stream) {
  const float* towers = (const float*)d_in[0];
  const float* agg    = (const float*)d_in[1];
  const float* MW1 = (const float*)d_in[2];
  const float* Mb1 = (const float*)d_in[3];
  const float* MW2 = (const float*)d_in[4];
  const float* Mb2 = (const float*)d_in[5];
  const float* MW3 = (const float*)d_in[6];
  const float* Mb3 = (const float*)d_in[7];
  const float* OW1 = (const float*)d_in[8];
  const float* Ob1 = (const float*)d_in[9];
  const float* OW2 = (const float*)d_in[10];
  const float* Ob2 = (const float*)d_in[11];
  const float* OW3 = (const float*)d_in[12];
  const float* Ob3 = (const float*)d_in[13];
  float* out = (float*)d_out;

  // ws layout (~90 MiB)
  _Float16* p = (_Float16*)d_ws;
  _Float16* W1catH = p; p += (size_t)2048 * 1088;   // [MW1t rows 0..1023 | OW1t 1024..2047]
  _Float16* MW2tH  = p; p += (size_t)1024 * 1024;
  _Float16* OW2tH  = p; p += (size_t)1024 * 1024;
  _Float16* MW3tH  = p; p += (size_t)1024 * 1024;
  _Float16* sumH   = p; p += (size_t)8192 * 1024;
  _Float16* mh1    = p; p += (size_t)8192 * 2048;   // m1 = cols 0..1023, h1 = 1024..2047
  _Float16* m2H    = p; p += (size_t)8192 * 1024;
  _Float16* towAllH = p; p += (size_t)16 * 8192 * 64;
  float* sacc  = (float*)p;
  float* b1cat = sacc + 8192;

  // per-call setup: transpose weights (fp16), concat W1/b1, towers, summary
  {
    int tot = 1088 * 1024;
    wconv_kernel<<<dim3((tot + 255) / 256), dim3(256), 0, stream>>>(MW1, 1088, 1024, W1catH);
    wconv_kernel<<<dim3((tot + 255) / 256), dim3(256), 0, stream>>>(OW1, 1088, 1024, W1catH + (size_t)1024 * 1088);
    tot = 1024 * 1024;
    wconv_kernel<<<dim3((tot + 255) / 256), dim3(256), 0, stream>>>(MW2, 1024, 1024, MW2tH);
    wconv_kernel<<<dim3((tot + 255) / 256), dim3(256), 0, stream>>>(OW2, 1024, 1024, OW2tH);
    wconv_kernel<<<dim3((tot + 255) / 256), dim3(256), 0, stream>>>(MW3, 1024, 1024, MW3tH);
    biascat_kernel<<<dim3(8), dim3(256), 0, stream>>>(Mb1, Ob1, b1cat);
    init_summary_kernel<<<dim3(32768), dim3(256), 0, stream>>>(agg, sumH, sacc);
    tow_conv_all_kernel<<<dim3(32768), dim3(256), 0, stream>>>(towers, towAllH);
  }

  const dim3 G1(64, 16), G(64, 8), B256(256);  // 128x128 tiles
  for (int k = 0; k < 16; ++k) {
    const _Float16* towH = towAllH + (size_t)k * 8192 * 64;

    // K1 (fused K1m+K1h): x=[sum|tow] @ W1cat^T -> mh1 (m1|h1), N=2048
    gemm_h_kernel<<<G1, B256, 0, stream>>>(sumH, 1024, towH, 64, 1024, 1088,
                                           W1catH, b1cat, mh1, 2048, nullptr, nullptr);
    // K2m: m1 @ MW2^T -> m2
    gemm_h_kernel<<<G, B256, 0, stream>>>(mh1, 2048, mh1, 2048, 1024, 1024,
                                          MW2tH, Mb2, m2H, 1024, nullptr, nullptr);
    // K2h: h1 @ OW2^T -> fused relu+dot(OW3) into sacc
    gemm_h_kernel<<<G, B256, 0, stream>>>(mh1 + 1024, 2048, mh1 + 1024, 2048, 1024, 1024,
                                          OW2tH, Ob2, nullptr, 1024, OW3, sacc);
    // K3: m2 @ MW3^T -> summary
    gemm_h_kernel<<<G, B256, 0, stream>>>(m2H, 1024, m2H, 1024, 1024, 1024,
                                          MW3tH, Mb3, sumH, 1024, nullptr, nullptr);
    // pred + product accumulate + re-zero sacc
    pred_final_kernel<<<dim3(32), dim3(256), 0, stream>>>(sacc, Ob3, out, k);
  }
}

// Round 11
// 2007.443 us; speedup vs baseline: 1.2227x; 1.0496x over previous
//
#include <hip/hip_runtime.h>
#include <cstdint>
#include <cstddef>

// BottomUpNet: N=8192 rows independent; K=16 sequential steps.
// R22 = R21 + dispatch fusion. R21 measured: K1 (1024 blocks, 4/CU) =
// 785 TF vs K2-type (512 blocks, 2/CU) = 688 TF — fill, not inner loop,
// is the remaining gradient (GEMM structure is at the plain-HIP ceiling
// per R12-R20's exhaustive schedule sweep). Changes:
//  (1) K2m+K2h fused via blockIdx.z (grid 64x8x2 = 1024 blocks = 4/CU):
//      independent GEMMs (A = mh1 halves, different B/epilogue) co-
//      scheduled; K2 pair should approach K1's efficiency; -1 launch.
//  (2) pred_final folded into K3's dispatch (grid 64x9: by==8 & bx<32
//      blocks run pred). pred reads sacc (complete from K2 dispatch),
//      K3's GEMM blocks never touch sacc/out — stream-order safe; -1
//      launch, pred hidden under K3 tail.
// GEMM core = R11/R21 verbatim (128x128, BK=64, 1-phase, 32KB LDS,
// launch_bounds(256,3)), refactored to a __device__ fn w/ single call
// site per kernel (keeps 32KB LDS). Zero arithmetic changes:
// absmax must stay exactly 1.192093e-07.

typedef _Float16 f16x8 __attribute__((ext_vector_type(8)));
typedef float f32x16 __attribute__((ext_vector_type(16)));

__device__ __forceinline__ void gload16(const void* g, void* l) {
  // async global->LDS, 16B/lane, LDS dest = wave-uniform base + lane*16
  __builtin_amdgcn_global_load_lds(
      (__attribute__((address_space(1))) void*)const_cast<void*>(g),
      (__attribute__((address_space(3))) void*)l,
      16, 0, 0);
}

// ---- fp16 GEMM core (R11 structure): C = relu(A@B^T + bias) fp16 out,
// or fused-pred mode (sacc != null): sacc[row] += sum_col relu(.)*w3[col]
// Tile 128x128, BK=64, single-buffered 32KB LDS, 256 thr (4 waves, 64x64).
__device__ __forceinline__ void gemm_core(
    const _Float16* __restrict__ A0, int ldA0,
    const _Float16* __restrict__ A1, int ldA1,
    int kcut, int Ktot,
    const _Float16* __restrict__ B,
    const float* __restrict__ bias,
    _Float16* __restrict__ C, int ldC,
    const float* __restrict__ w3, float* __restrict__ sacc,
    int mBase, int nBase)
{
  __shared__ _Float16 sAh[128 * 64];
  __shared__ _Float16 sBh[128 * 64];

  const int lane = threadIdx.x & 63;
  const int wave = threadIdx.x >> 6;
  const int wm = (wave >> 1) * 64, wn = (wave & 1) * 64;

  // staging coords: 8 rows/chunk (128 B rows), 8 lanes/row (16 B each);
  // physical seg in LDS = lane-seg, global source seg = lane-seg ^ (row&7)
  const int lr = lane >> 3;                 // row within chunk (0..7)
  const int lcs8 = ((lane & 7) ^ lr) * 8;   // swizzled source seg offset (halves)

  // fragment coords + read-side swizzle (row&7 == l31&7)
  const int l31 = lane & 31, l5 = lane >> 5;
  const int fswz = l31 & 7;

  f32x16 acc[2][2];
#pragma unroll
  for (int i = 0; i < 2; ++i)
#pragma unroll
    for (int j = 0; j < 2; ++j)
      acc[i][j] = (f32x16)0.0f;

  for (int kt = 0; kt < Ktot; kt += 64) {
    const _Float16* aH; int pA, kl;
    if (kt < kcut) { aH = A0; pA = ldA0; kl = kt; }
    else           { aH = A1; pA = ldA1; kl = kt - kcut; }

#pragma unroll
    for (int cc = 0; cc < 4; ++cc) {
      const int c = wave * 4 + cc;                  // chunk 0..15, 8 rows each
      const int arow = mBase + c * 8 + lr;
      const int brow = nBase + c * 8 + lr;
      gload16(aH + (size_t)arow * pA   + kl + lcs8, &sAh[c * 512]);
      gload16(B  + (size_t)brow * Ktot + kt + lcs8, &sBh[c * 512]);
    }
    __syncthreads();

#pragma unroll
    for (int kh = 0; kh < 4; ++kh) {                // four K=16 MFMAs per BK=64
      const int ko = ((kh * 2 + l5) ^ fswz) * 8;    // swizzled seg (0..7)
      f16x8 ah[2], bh[2];
#pragma unroll
      for (int i = 0; i < 2; ++i)
        ah[i] = *(const f16x8*)&sAh[(wm + i * 32 + l31) * 64 + ko];
#pragma unroll
      for (int j = 0; j < 2; ++j)
        bh[j] = *(const f16x8*)&sBh[(wn + j * 32 + l31) * 64 + ko];
#pragma unroll
      for (int i = 0; i < 2; ++i)
#pragma unroll
        for (int j = 0; j < 2; ++j)
          acc[i][j] = __builtin_amdgcn_mfma_f32_32x32x16_f16(ah[i], bh[j], acc[i][j], 0, 0, 0);
    }
    __syncthreads();
  }

  float bv[2], w3v[2];
#pragma unroll
  for (int j = 0; j < 2; ++j) {
    const int col = nBase + wn + j * 32 + l31;
    bv[j] = bias[col];
    w3v[j] = sacc ? w3[col] : 0.0f;
  }

  if (sacc) {
    // fused pred partial: one value per C/D row, reduced over the 32 col-lanes
#pragma unroll
    for (int i = 0; i < 2; ++i)
#pragma unroll
      for (int r = 0; r < 16; ++r) {
        float pr = 0.0f;
#pragma unroll
        for (int j = 0; j < 2; ++j)
          pr += fmaxf(acc[i][j][r] + bv[j], 0.0f) * w3v[j];
        pr += __shfl_xor(pr, 1);
        pr += __shfl_xor(pr, 2);
        pr += __shfl_xor(pr, 4);
        pr += __shfl_xor(pr, 8);
        pr += __shfl_xor(pr, 16);
        if (l31 == 0)
          atomicAdd(&sacc[mBase + wm + i * 32 + (r & 3) + 8 * (r >> 2) + 4 * l5], pr);
      }
  } else {
#pragma unroll
    for (int i = 0; i < 2; ++i)
#pragma unroll
      for (int j = 0; j < 2; ++j)
#pragma unroll
        for (int r = 0; r < 16; ++r) {
          const int row = mBase + wm + i * 32 + (r & 3) + 8 * (r >> 2) + 4 * l5;
          const int col = nBase + wn + j * 32 + l31;
          float v = fmaxf(acc[i][j][r] + bv[j], 0.0f);
          C[(size_t)row * ldC + col] = (_Float16)v;
        }
  }
}

// K1: x=[sum|tow] @ W1cat^T -> mh1, N=2048. grid (64,16).
__global__ __launch_bounds__(256, 3)
void gemm_h_kernel(const _Float16* __restrict__ A0, int ldA0,
                   const _Float16* __restrict__ A1, int ldA1,
                   int kcut, int Ktot,
                   const _Float16* __restrict__ B,
                   const float* __restrict__ bias,
                   _Float16* __restrict__ C, int ldC,
                   const float* __restrict__ w3, float* __restrict__ sacc)
{
  gemm_core(A0, ldA0, A1, ldA1, kcut, Ktot, B, bias, C, ldC, w3, sacc,
            blockIdx.x * 128, blockIdx.y * 128);
}

// K2 pair: z=0 -> m-chain (mh1 lo @ Bm -> Cm); z=1 -> h-chain fused pred
// (mh1 hi @ Bh -> sacc). grid (64,8,2) = 1024 blocks.
__global__ __launch_bounds__(256, 3)
void gemm_pair_kernel(const _Float16* __restrict__ Am,
                      const _Float16* __restrict__ Ah, int ldA, int Ktot,
                      const _Float16* __restrict__ Bm,
                      const _Float16* __restrict__ Bh,
                      const float* __restrict__ biasm,
                      const float* __restrict__ biash,
                      _Float16* __restrict__ Cm, int ldCm,
                      const float* __restrict__ w3, float* __restrict__ sacc)
{
  const bool h = (blockIdx.z != 0);
  gemm_core(h ? Ah : Am, ldA, h ? Ah : Am, ldA, Ktot, Ktot,
            h ? Bh : Bm, h ? biash : biasm,
            h ? nullptr : Cm, ldCm,
            h ? w3 : nullptr, h ? sacc : nullptr,
            blockIdx.x * 128, blockIdx.y * 128);
}

// K3 + pred: by<8 -> GEMM (m2 @ MW3^T -> sumH); by==8 & bx<32 -> pred
// (sigmoid(sacc+b3), out *=, sacc=0). grid (64,9).
__global__ __launch_bounds__(256, 3)
void gemm_pred_kernel(const _Float16* __restrict__ A, int ldA, int Ktot,
                      const _Float16* __restrict__ B,
                      const float* __restrict__ bias,
                      _Float16* __restrict__ C, int ldC,
                      float* __restrict__ sacc, const float* __restrict__ b3,
                      float* __restrict__ out, int step)
{
  if (blockIdx.y == 8) {
    if (blockIdx.x < 32) {
      const int row = blockIdx.x * 256 + threadIdx.x;   // 8192 rows
      float pv = 1.0f / (1.0f + expf(-(sacc[row] + b3[0])));
      out[row] = (step == 0) ? pv : out[row] * pv;
      sacc[row] = 0.0f;
    }
    return;
  }
  gemm_core(A, ldA, A, ldA, Ktot, Ktot, B, bias, C, ldC, nullptr, nullptr,
            blockIdx.x * 128, blockIdx.y * 128);
}

// W (K x N fp32, row-major) -> out (N x K fp16), i.e. transposed
__global__ void wconv_kernel(const float* __restrict__ W, int K, int N,
                             _Float16* __restrict__ oH) {
  int idx = blockIdx.x * 256 + threadIdx.x;   // idx = n*K + k (output-coalesced)
  if (idx >= K * N) return;
  int n = idx / K, k = idx - n * K;
  oH[idx] = (_Float16)W[(size_t)k * N + n];
}

__global__ void init_summary_kernel(const float* __restrict__ agg,
                                    _Float16* __restrict__ sH,
                                    float* __restrict__ sacc) {
  int idx = blockIdx.x * 256 + threadIdx.x;   // 8192*1024
  sH[idx] = (_Float16)agg[idx & 1023];
  if (idx < 8192) sacc[idx] = 0.0f;
}

// bias concat: b1cat = [Mb1 | Ob1] (2048 floats)
__global__ void biascat_kernel(const float* __restrict__ b0,
                               const float* __restrict__ b1,
                               float* __restrict__ o) {
  int idx = blockIdx.x * 256 + threadIdx.x;   // 2048
  o[idx] = (idx < 1024) ? b0[idx] : b1[idx - 1024];
}

// towers [n][k][f] fp32 -> towAll [k][n][f] fp16 (all 16 slices)
__global__ void tow_conv_all_kernel(const float* __restrict__ towers,
                                    _Float16* __restrict__ oH) {
  size_t idx = (size_t)blockIdx.x * 256 + threadIdx.x;  // (k*8192+n)*64+f
  int f = idx & 63;
  int n = (int)((idx >> 6) & 8191);
  int k = (int)(idx >> 19);
  oH[idx] = (_Float16)towers[((size_t)n * 16 + k) * 64 + f];
}

extern "C" void kernel_launch(void* const* d_in, const int* in_sizes, int n_in,
                              void* d_out, int out_size, void* d_ws, size_t ws_size,
                              hipStream_t stream) {
  const float* towers = (const float*)d_in[0];
  const float* agg    = (const float*)d_in[1];
  const float* MW1 = (const float*)d_in[2];
  const float* Mb1 = (const float*)d_in[3];
  const float* MW2 = (const float*)d_in[4];
  const float* Mb2 = (const float*)d_in[5];
  const float* MW3 = (const float*)d_in[6];
  const float* Mb3 = (const float*)d_in[7];
  const float* OW1 = (const float*)d_in[8];
  const float* Ob1 = (const float*)d_in[9];
  const float* OW2 = (const float*)d_in[10];
  const float* Ob2 = (const float*)d_in[11];
  const float* OW3 = (const float*)d_in[12];
  const float* Ob3 = (const float*)d_in[13];
  float* out = (float*)d_out;

  // ws layout (~90 MiB)
  _Float16* p = (_Float16*)d_ws;
  _Float16* W1catH = p; p += (size_t)2048 * 1088;   // [MW1t rows 0..1023 | OW1t 1024..2047]
  _Float16* MW2tH  = p; p += (size_t)1024 * 1024;
  _Float16* OW2tH  = p; p += (size_t)1024 * 1024;
  _Float16* MW3tH  = p; p += (size_t)1024 * 1024;
  _Float16* sumH   = p; p += (size_t)8192 * 1024;
  _Float16* mh1    = p; p += (size_t)8192 * 2048;   // m1 = cols 0..1023, h1 = 1024..2047
  _Float16* m2H    = p; p += (size_t)8192 * 1024;
  _Float16* towAllH = p; p += (size_t)16 * 8192 * 64;
  float* sacc  = (float*)p;
  float* b1cat = sacc + 8192;

  // per-call setup: transpose weights (fp16), concat W1/b1, towers, summary
  {
    int tot = 1088 * 1024;
    wconv_kernel<<<dim3((tot + 255) / 256), dim3(256), 0, stream>>>(MW1, 1088, 1024, W1catH);
    wconv_kernel<<<dim3((tot + 255) / 256), dim3(256), 0, stream>>>(OW1, 1088, 1024, W1catH + (size_t)1024 * 1088);
    tot = 1024 * 1024;
    wconv_kernel<<<dim3((tot + 255) / 256), dim3(256), 0, stream>>>(MW2, 1024, 1024, MW2tH);
    wconv_kernel<<<dim3((tot + 255) / 256), dim3(256), 0, stream>>>(OW2, 1024, 1024, OW2tH);
    wconv_kernel<<<dim3((tot + 255) / 256), dim3(256), 0, stream>>>(MW3, 1024, 1024, MW3tH);
    biascat_kernel<<<dim3(8), dim3(256), 0, stream>>>(Mb1, Ob1, b1cat);
    init_summary_kernel<<<dim3(32768), dim3(256), 0, stream>>>(agg, sumH, sacc);
    tow_conv_all_kernel<<<dim3(32768), dim3(256), 0, stream>>>(towers, towAllH);
  }

  const dim3 G1(64, 16), G2(64, 8, 2), G3(64, 9), B256(256);  // 128x128 tiles
  for (int k = 0; k < 16; ++k) {
    const _Float16* towH = towAllH + (size_t)k * 8192 * 64;

    // K1 (fused K1m+K1h): x=[sum|tow] @ W1cat^T -> mh1 (m1|h1), N=2048
    gemm_h_kernel<<<G1, B256, 0, stream>>>(sumH, 1024, towH, 64, 1024, 1088,
                                           W1catH, b1cat, mh1, 2048, nullptr, nullptr);
    // K2 pair: z=0: m1 @ MW2^T -> m2 ; z=1: h1 @ OW2^T -> relu+dot(OW3) -> sacc
    gemm_pair_kernel<<<G2, B256, 0, stream>>>(mh1, mh1 + 1024, 2048, 1024,
                                              MW2tH, OW2tH, Mb2, Ob2,
                                              m2H, 1024, OW3, sacc);
    // K3 + pred: m2 @ MW3^T -> summary ; by==8: pred product accumulate
    gemm_pred_kernel<<<G3, B256, 0, stream>>>(m2H, 1024, 1024, MW3tH, Mb3,
                                              sumH, 1024, sacc, Ob3, out, k);
  }
}